// Round 2
// baseline (2499.143 us; speedup 1.0000x reference)
//
#include <hip/hip_runtime.h>

#define N_NODES 50000
#define D_FEAT 128
#define N_EDGES 1600000
#define NUM_ITERS 20

// ---------------- mask dtype detection ---------------------------------------
// Reads the first N_NODES*D_FEAT bytes (minimum buffer size across layouts) as
// u32 words. Sets bit0 if any word not in {0,1}; bit1 if any word == 0x3f800000.
//   bit0==0            -> int32 mask (values 0/1)
//   bit0==1 && bit1==1 -> float32 mask (0.0f / 1.0f; bool-bytes can't form 0x3f800000)
//   bit0==1 && bit1==0 -> uint8 mask
__global__ void detect_kernel(const unsigned int* __restrict__ w, int nwords,
                              unsigned int* __restrict__ flags) {
    int i = blockIdx.x * blockDim.x + threadIdx.x;
    int stride = gridDim.x * blockDim.x;
    unsigned int f = 0;
    for (; i < nwords; i += stride) {
        unsigned int v = w[i];
        if (v > 1u) f |= 1u;
        if (v == 0x3f800000u) f |= 2u;
    }
    if (f) atomicOr(flags, f);
}

// ---------------- normalize mask to uint8 ------------------------------------
__global__ void build_mask_kernel(const void* __restrict__ mask,
                                  const unsigned int* __restrict__ flags,
                                  unsigned char* __restrict__ m8, int n) {
    int i = blockIdx.x * blockDim.x + threadIdx.x;
    if (i >= n) return;
    unsigned int fl = *flags;
    int mv;
    if ((fl & 1u) == 0u) {
        mv = ((const int*)mask)[i];                     // int32 0/1
    } else if (fl & 2u) {
        mv = (((const float*)mask)[i] != 0.0f) ? 1 : 0; // float32
    } else {
        mv = ((const unsigned char*)mask)[i];           // uint8 bool
    }
    m8[i] = mv ? 1 : 0;
}

// ---------------- degree counting (col for weights, row for CSR) -------------
__global__ void degree_kernel(const int* __restrict__ row, const int* __restrict__ col,
                              int* __restrict__ deg_col, int* __restrict__ cnt_row, int n) {
    int i = blockIdx.x * blockDim.x + threadIdx.x;
    int stride = gridDim.x * blockDim.x;
    for (; i < n; i += stride) {
        atomicAdd(&deg_col[col[i]], 1);
        atomicAdd(&cnt_row[row[i]], 1);
    }
}

// ---------------- deg^-1/2 ---------------------------------------------------
__global__ void dis_kernel(const int* __restrict__ deg, float* __restrict__ dis, int n) {
    int i = blockIdx.x * blockDim.x + threadIdx.x;
    if (i < n) {
        int d = deg[i];
        dis[i] = (d > 0) ? rsqrtf((float)d) : 0.0f;
    }
}

// ---------------- single-block chunked exclusive scan ------------------------
__global__ void scan_kernel(const int* __restrict__ cnt, int* __restrict__ offsets,
                            int* __restrict__ cursor, int n, int total) {
    __shared__ int tmp[1024];
    __shared__ int s_carry;
    if (threadIdx.x == 0) s_carry = 0;
    __syncthreads();
    for (int base = 0; base < n; base += 1024) {
        int i = base + (int)threadIdx.x;
        int v = (i < n) ? cnt[i] : 0;
        tmp[threadIdx.x] = v;
        __syncthreads();
        for (int off = 1; off < 1024; off <<= 1) {
            int t = (threadIdx.x >= (unsigned)off) ? tmp[threadIdx.x - off] : 0;
            __syncthreads();
            tmp[threadIdx.x] += t;
            __syncthreads();
        }
        int incl = tmp[threadIdx.x];
        int excl = incl - v;
        int carry = s_carry;
        if (i < n) {
            offsets[i] = carry + excl;
            cursor[i]  = carry + excl;
        }
        __syncthreads();
        if (threadIdx.x == 1023) s_carry = carry + tmp[1023];
        __syncthreads();
    }
    if (threadIdx.x == 0) offsets[n] = total;
}

// ---------------- scatter edges into CSR ------------------------------------
__global__ void scatter_kernel(const int* __restrict__ row, const int* __restrict__ col,
                               const float* __restrict__ dis, int* __restrict__ cursor,
                               int* __restrict__ csr_col, float* __restrict__ csr_w, int n) {
    int i = blockIdx.x * blockDim.x + threadIdx.x;
    int stride = gridDim.x * blockDim.x;
    for (; i < n; i += stride) {
        int r = row[i];
        int c = col[i];
        int pos = atomicAdd(&cursor[r], 1);
        csr_col[pos] = c;
        csr_w[pos] = dis[r] * dis[c];
    }
}

// ---------------- out0 = mask ? x : 0 ----------------------------------------
__global__ void init_kernel(const float* __restrict__ x, const unsigned char* __restrict__ m8,
                            float* __restrict__ out, int n) {
    int i = blockIdx.x * blockDim.x + threadIdx.x;
    if (i < n) out[i] = m8[i] ? x[i] : 0.0f;
}

// ---------------- one propagation step: nxt = mask ? x : A_hat @ cur ---------
__global__ void __launch_bounds__(128) prop_kernel(const int* __restrict__ offsets,
                                                   const int* __restrict__ csr_col,
                                                   const float* __restrict__ csr_w,
                                                   const float* __restrict__ cur,
                                                   const float* __restrict__ x,
                                                   const unsigned char* __restrict__ m8,
                                                   float* __restrict__ nxt) {
    const int node = blockIdx.x;
    const int f = threadIdx.x;  // 0..127, one feature per lane
    const int s = offsets[node];
    const int e = offsets[node + 1];

    __shared__ int   sc[128];
    __shared__ float sw[128];

    float acc = 0.0f;
    for (int base = s; base < e; base += 128) {
        int nn = e - base;
        if (nn > 128) nn = 128;
        if (f < nn) {
            sc[f] = csr_col[base + f];
            sw[f] = csr_w[base + f];
        }
        __syncthreads();
        for (int j = 0; j < nn; ++j) {
            acc += sw[j] * cur[sc[j] * D_FEAT + f];
        }
        __syncthreads();
    }

    const int idx = node * D_FEAT + f;
    nxt[idx] = m8[idx] ? x[idx] : acc;
}

extern "C" void kernel_launch(void* const* d_in, const int* in_sizes, int n_in,
                              void* d_out, int out_size, void* d_ws, size_t ws_size,
                              hipStream_t stream) {
    const float* x = (const float*)d_in[0];
    const int* edge = (const int*)d_in[1];
    const void* mask = d_in[2];
    const int* row = edge;             // edge_index[0]
    const int* col = edge + N_EDGES;   // edge_index[1]
    float* out = (float*)d_out;

    // workspace carve-up (256B aligned)
    char* ws = (char*)d_ws;
    size_t off = 0;
    auto alloc = [&](size_t bytes) -> void* {
        void* p = ws + off;
        off += (bytes + 255) & ~(size_t)255;
        return p;
    };
    int*   deg_col = (int*)alloc((size_t)N_NODES * 4);
    int*   cnt_row = (int*)alloc((size_t)N_NODES * 4);
    int*   offsets = (int*)alloc((size_t)(N_NODES + 1) * 4);
    int*   cursor  = (int*)alloc((size_t)N_NODES * 4);
    float* dis     = (float*)alloc((size_t)N_NODES * 4);
    unsigned int* flags = (unsigned int*)alloc(256);
    unsigned char* m8 = (unsigned char*)alloc((size_t)N_NODES * D_FEAT);
    int*   csr_col = (int*)alloc((size_t)N_EDGES * 4);
    float* csr_w   = (float*)alloc((size_t)N_EDGES * 4);
    float* buf     = (float*)alloc((size_t)N_NODES * D_FEAT * 4);

    hipMemsetAsync(deg_col, 0, (size_t)N_NODES * 4, stream);
    hipMemsetAsync(cnt_row, 0, (size_t)N_NODES * 4, stream);
    hipMemsetAsync(flags, 0, 4, stream);

    const int total_feat = N_NODES * D_FEAT;
    const int mask_words = total_feat / 4;  // minimum size across layouts

    detect_kernel<<<1024, 256, 0, stream>>>((const unsigned int*)mask, mask_words, flags);
    build_mask_kernel<<<(total_feat + 255) / 256, 256, 0, stream>>>(mask, flags, m8, total_feat);

    degree_kernel<<<1024, 256, 0, stream>>>(row, col, deg_col, cnt_row, N_EDGES);
    dis_kernel<<<(N_NODES + 255) / 256, 256, 0, stream>>>(deg_col, dis, N_NODES);
    scan_kernel<<<1, 1024, 0, stream>>>(cnt_row, offsets, cursor, N_NODES, N_EDGES);
    scatter_kernel<<<1024, 256, 0, stream>>>(row, col, dis, cursor, csr_col, csr_w, N_EDGES);

    init_kernel<<<(total_feat + 255) / 256, 256, 0, stream>>>(x, m8, out, total_feat);

    for (int it = 0; it < NUM_ITERS; ++it) {
        const float* src = (it % 2 == 0) ? out : buf;
        float*       dst = (it % 2 == 0) ? buf : out;
        prop_kernel<<<N_NODES, 128, 0, stream>>>(offsets, csr_col, csr_w, src, x, m8, dst);
    }
}

// Round 3
// 1416.045 us; speedup vs baseline: 1.7649x; 1.7649x over previous
//
#include <hip/hip_runtime.h>

#define N_NODES 50000
#define D_FEAT 128
#define N_EDGES 1600000
#define NUM_ITERS 20

typedef unsigned int u32;
typedef unsigned short u16;

__device__ __forceinline__ u16 bf16_rne(float f) {
    u32 u = __float_as_uint(f);
    u32 r = u + 0x7fffu + ((u >> 16) & 1u);
    return (u16)(r >> 16);
}

// ---------------- mask dtype detection ---------------------------------------
// Reads the first N_NODES*D_FEAT bytes (minimum buffer size across layouts) as
// u32 words. bit0: any word not in {0,1}; bit1: any word == 0x3f800000.
//   bit0==0            -> int32 mask
//   bit0==1 && bit1==1 -> float32 mask
//   bit0==1 && bit1==0 -> uint8 mask
__global__ void detect_kernel(const u32* __restrict__ w, int nwords,
                              u32* __restrict__ flags) {
    int i = blockIdx.x * blockDim.x + threadIdx.x;
    int stride = gridDim.x * blockDim.x;
    u32 f = 0;
    for (; i < nwords; i += stride) {
        u32 v = w[i];
        if (v > 1u) f |= 1u;
        if (v == 0x3f800000u) f |= 2u;
    }
    if (f) atomicOr(flags, f);
}

// ---------------- normalize mask to uint8 + init state (bf16) ----------------
__global__ void build_kernel(const void* __restrict__ mask,
                             const u32* __restrict__ flags,
                             const float* __restrict__ x,
                             unsigned char* __restrict__ m8,
                             u16* __restrict__ st0, int n) {
    int i = blockIdx.x * blockDim.x + threadIdx.x;
    if (i >= n) return;
    u32 fl = *flags;
    int mv;
    if ((fl & 1u) == 0u) {
        mv = ((const int*)mask)[i];
    } else if (fl & 2u) {
        mv = (((const float*)mask)[i] != 0.0f) ? 1 : 0;
    } else {
        mv = ((const unsigned char*)mask)[i];
    }
    m8[i] = mv ? 1 : 0;
    st0[i] = mv ? bf16_rne(x[i]) : (u16)0;
}

// ---------------- degree counting (col for weights, row for CSR) -------------
__global__ void degree_kernel(const int* __restrict__ row, const int* __restrict__ col,
                              int* __restrict__ deg_col, int* __restrict__ cnt_row, int n) {
    int i = blockIdx.x * blockDim.x + threadIdx.x;
    int stride = gridDim.x * blockDim.x;
    for (; i < n; i += stride) {
        atomicAdd(&deg_col[col[i]], 1);
        atomicAdd(&cnt_row[row[i]], 1);
    }
}

// ---------------- deg^-1/2 ---------------------------------------------------
__global__ void dis_kernel(const int* __restrict__ deg, float* __restrict__ dis, int n) {
    int i = blockIdx.x * blockDim.x + threadIdx.x;
    if (i < n) {
        int d = deg[i];
        dis[i] = (d > 0) ? rsqrtf((float)d) : 0.0f;
    }
}

// ---------------- single-block scan (wave-shuffle, few barriers) -------------
__global__ void __launch_bounds__(1024) scan_kernel(const int* __restrict__ cnt,
                                                    int* __restrict__ offsets,
                                                    int* __restrict__ cursor,
                                                    int n, int total) {
    __shared__ int wsum[16];
    __shared__ int s_carry;
    const int tid = threadIdx.x;
    const int lane = tid & 63, wid = tid >> 6;
    if (tid == 0) s_carry = 0;
    __syncthreads();
    for (int base = 0; base < n; base += 1024) {
        int i = base + tid;
        int v = (i < n) ? cnt[i] : 0;
        int incl = v;
        #pragma unroll
        for (int off = 1; off < 64; off <<= 1) {
            int t = __shfl_up(incl, off);
            if (lane >= off) incl += t;
        }
        if (lane == 63) wsum[wid] = incl;
        __syncthreads();
        if (tid < 16) {
            int s = wsum[tid];
            #pragma unroll
            for (int off = 1; off < 16; off <<= 1) {
                int t = __shfl_up(s, off);
                if (tid >= off) s += t;
            }
            wsum[tid] = s;
        }
        __syncthreads();
        int carry = s_carry;
        int excl = carry + (wid ? wsum[wid - 1] : 0) + incl - v;
        if (i < n) { offsets[i] = excl; cursor[i] = excl; }
        __syncthreads();
        if (tid == 0) s_carry = carry + wsum[15];
        __syncthreads();
    }
    if (tid == 0) offsets[n] = total;
}

// ---------------- scatter edges into packed CSR (8B per edge) ----------------
__global__ void scatter_kernel(const int* __restrict__ row, const int* __restrict__ col,
                               const float* __restrict__ dis, int* __restrict__ cursor,
                               uint2* __restrict__ csr_cw, int n) {
    int i = blockIdx.x * blockDim.x + threadIdx.x;
    int stride = gridDim.x * blockDim.x;
    for (; i < n; i += stride) {
        int r = row[i];
        int c = col[i];
        int pos = atomicAdd(&cursor[r], 1);
        csr_cw[pos] = make_uint2((u32)c, __float_as_uint(dis[r] * dis[c]));
    }
}

// ---------------- one propagation step ---------------------------------------
// One wave per node. lane = eg*16 + fl: eg (0..3) = edge slot, fl (0..15) =
// feature group (8 bf16 = 16B per lane). 4 edges gathered per chunk, butterfly
// reduce across eg at the end.
template <bool FINAL>
__global__ void __launch_bounds__(256) prop_kernel(const int* __restrict__ offsets,
                                                   const uint2* __restrict__ csr_cw,
                                                   const u16* __restrict__ cur,
                                                   const float* __restrict__ x,
                                                   const unsigned char* __restrict__ m8,
                                                   void* __restrict__ nxtp) {
    const int tid = threadIdx.x;
    const int wid = tid >> 6, lane = tid & 63;
    const int node = blockIdx.x * 4 + wid;
    if (node >= N_NODES) return;
    const int fl = lane & 15, eg = lane >> 4;
    const int s = offsets[node], e = offsets[node + 1];

    float a0 = 0, a1 = 0, a2 = 0, a3 = 0, a4 = 0, a5 = 0, a6 = 0, a7 = 0;
    #pragma unroll 2
    for (int base = s; base < e; base += 4) {
        const int ei = base + eg;
        uint2 cw = make_uint2(0u, 0u);
        if (ei < e) cw = csr_cw[ei];
        const float w = __uint_as_float(cw.y);
        const uint4 r = *((const uint4*)(cur + (size_t)cw.x * D_FEAT) + fl);
        a0 = fmaf(w, __uint_as_float(r.x << 16), a0);
        a1 = fmaf(w, __uint_as_float(r.x & 0xffff0000u), a1);
        a2 = fmaf(w, __uint_as_float(r.y << 16), a2);
        a3 = fmaf(w, __uint_as_float(r.y & 0xffff0000u), a3);
        a4 = fmaf(w, __uint_as_float(r.z << 16), a4);
        a5 = fmaf(w, __uint_as_float(r.z & 0xffff0000u), a5);
        a6 = fmaf(w, __uint_as_float(r.w << 16), a6);
        a7 = fmaf(w, __uint_as_float(r.w & 0xffff0000u), a7);
    }
    a0 += __shfl_xor(a0, 16); a0 += __shfl_xor(a0, 32);
    a1 += __shfl_xor(a1, 16); a1 += __shfl_xor(a1, 32);
    a2 += __shfl_xor(a2, 16); a2 += __shfl_xor(a2, 32);
    a3 += __shfl_xor(a3, 16); a3 += __shfl_xor(a3, 32);
    a4 += __shfl_xor(a4, 16); a4 += __shfl_xor(a4, 32);
    a5 += __shfl_xor(a5, 16); a5 += __shfl_xor(a5, 32);
    a6 += __shfl_xor(a6, 16); a6 += __shfl_xor(a6, 32);
    a7 += __shfl_xor(a7, 16); a7 += __shfl_xor(a7, 32);

    if (eg == 0) {
        const int fbase = node * D_FEAT + fl * 8;
        const uint2 mu = *(const uint2*)(m8 + fbase);
        const float4 x0 = *(const float4*)(x + fbase);
        const float4 x1 = *(const float4*)(x + fbase + 4);
        const float v0 = (mu.x & 0x000000ffu) ? x0.x : a0;
        const float v1 = (mu.x & 0x0000ff00u) ? x0.y : a1;
        const float v2 = (mu.x & 0x00ff0000u) ? x0.z : a2;
        const float v3 = (mu.x & 0xff000000u) ? x0.w : a3;
        const float v4 = (mu.y & 0x000000ffu) ? x1.x : a4;
        const float v5 = (mu.y & 0x0000ff00u) ? x1.y : a5;
        const float v6 = (mu.y & 0x00ff0000u) ? x1.z : a6;
        const float v7 = (mu.y & 0xff000000u) ? x1.w : a7;
        if (FINAL) {
            float* outp = (float*)nxtp;
            *(float4*)(outp + fbase) = make_float4(v0, v1, v2, v3);
            *(float4*)(outp + fbase + 4) = make_float4(v4, v5, v6, v7);
        } else {
            u16* outp = (u16*)nxtp;
            uint4 st;
            st.x = (u32)bf16_rne(v0) | ((u32)bf16_rne(v1) << 16);
            st.y = (u32)bf16_rne(v2) | ((u32)bf16_rne(v3) << 16);
            st.z = (u32)bf16_rne(v4) | ((u32)bf16_rne(v5) << 16);
            st.w = (u32)bf16_rne(v6) | ((u32)bf16_rne(v7) << 16);
            *(uint4*)(outp + fbase) = st;
        }
    }
}

extern "C" void kernel_launch(void* const* d_in, const int* in_sizes, int n_in,
                              void* d_out, int out_size, void* d_ws, size_t ws_size,
                              hipStream_t stream) {
    const float* x = (const float*)d_in[0];
    const int* edge = (const int*)d_in[1];
    const void* mask = d_in[2];
    const int* row = edge;             // edge_index[0]
    const int* col = edge + N_EDGES;   // edge_index[1]
    float* out = (float*)d_out;

    // workspace carve-up (256B aligned)
    char* ws = (char*)d_ws;
    size_t off = 0;
    auto alloc = [&](size_t bytes) -> void* {
        void* p = ws + off;
        off += (bytes + 255) & ~(size_t)255;
        return p;
    };
    int* deg_col = (int*)alloc((size_t)N_NODES * 4);
    int* cnt_row = (int*)alloc((size_t)N_NODES * 4);
    int* offsets = (int*)alloc((size_t)(N_NODES + 1) * 4);
    int* cursor  = (int*)alloc((size_t)N_NODES * 4);
    float* dis   = (float*)alloc((size_t)N_NODES * 4);
    u32* flags   = (u32*)alloc(256);
    unsigned char* m8 = (unsigned char*)alloc((size_t)N_NODES * D_FEAT);
    uint2* csr_cw = (uint2*)alloc((size_t)N_EDGES * 8);
    u16* st0 = (u16*)alloc((size_t)N_NODES * D_FEAT * 2);
    u16* st1 = (u16*)alloc((size_t)N_NODES * D_FEAT * 2);

    hipMemsetAsync(deg_col, 0, (size_t)N_NODES * 4, stream);
    hipMemsetAsync(cnt_row, 0, (size_t)N_NODES * 4, stream);
    hipMemsetAsync(flags, 0, 4, stream);

    const int total_feat = N_NODES * D_FEAT;
    const int mask_words = total_feat / 4;  // minimum size across layouts

    detect_kernel<<<1024, 256, 0, stream>>>((const u32*)mask, mask_words, flags);
    build_kernel<<<(total_feat + 255) / 256, 256, 0, stream>>>(mask, flags, x, m8, st0, total_feat);

    degree_kernel<<<2048, 256, 0, stream>>>(row, col, deg_col, cnt_row, N_EDGES);
    dis_kernel<<<(N_NODES + 255) / 256, 256, 0, stream>>>(deg_col, dis, N_NODES);
    scan_kernel<<<1, 1024, 0, stream>>>(cnt_row, offsets, cursor, N_NODES, N_EDGES);
    scatter_kernel<<<2048, 256, 0, stream>>>(row, col, dis, cursor, csr_cw, N_EDGES);

    const int prop_blocks = (N_NODES + 3) / 4;
    for (int it = 0; it < NUM_ITERS; ++it) {
        const u16* src = (it & 1) ? st1 : st0;
        if (it < NUM_ITERS - 1) {
            u16* dst = (it & 1) ? st0 : st1;
            prop_kernel<false><<<prop_blocks, 256, 0, stream>>>(offsets, csr_cw, src, x, m8, dst);
        } else {
            prop_kernel<true><<<prop_blocks, 256, 0, stream>>>(offsets, csr_cw, src, x, m8, out);
        }
    }
}